// Round 10
// baseline (696.610 us; speedup 1.0000x reference)
//
#include <hip/hip_runtime.h>

// Pipeline (node features: packed bf16 pairs, SLICE-MAJOR g[8][N][8 dwords];
// slice s holds channels [32s, 32s+32), word w = channels 2w,2w+1 of slice):
//  tile_hist (+zero counts/stats) -> scan(tcnt) -> tile_scatter (radix: edges
//  bucket-grouped by dst>>9, coalesced writes) -> deg_count -> scan(counts,
//  +dinv) -> bucket_sort (LDS counting sort, sequential writes -> sorted[] CSR)
//  -> gemm<0> (g1 = dinv .* bf16(x@W1), slice-major; b1 cancels in BN)
//  -> gather (slice-per-XCD: random reads hit a 3.2MB L2-resident slice)
//  -> bn_stats -> gemm<1> (BN+ReLU fused on A-path) -> gather -> gstart
//  -> pool (+b2) -> head
//
// HW laws measured this session:
//  - scattered dword stores: ~40-64B HBM writeback each; L2 never assembles
//    lines -> all sort-pipeline stores are sequential.
//  - gather on full 25.6MB table: FETCH = 8 XCD x table (L2 too small);
//    ~3.5 TB/s random-256B ceiling. Fix: 16-channel slices (3.2MB/XCD, L2-fits).
//  - low-grid kernels (<1 block/CU) are latency-exposed -> 3+ blocks/CU.

typedef __attribute__((ext_vector_type(8))) short bf16x8;
typedef __attribute__((ext_vector_type(4))) float f32x4;
typedef __attribute__((ext_vector_type(4))) unsigned u32x4;

#define NBKT_MAX 256
#define BKT_SHIFT 9            // bucket = dst >> 9 (512 nodes per bucket)
#define TILE_E 2000            // edges per radix tile
#define BSORT_CAP 4096         // LDS staging cap per node-quarter

__device__ __forceinline__ float bf_lo(unsigned u) {
  union { unsigned u; float f; } c; c.u = u << 16; return c.f;
}
__device__ __forceinline__ float bf_hi(unsigned u) {
  union { unsigned u; float f; } c; c.u = u & 0xffff0000u; return c.f;
}
__device__ __forceinline__ unsigned short f32_bf16(float f) {
  union { float f; unsigned u; } c; c.f = f;
  return (unsigned short)((c.u + 0x7fffu + ((c.u >> 16) & 1u)) >> 16);  // RNE
}
__device__ __forceinline__ unsigned pack_bf16(float a, float b) {
  return (unsigned)f32_bf16(a) | ((unsigned)f32_bf16(b) << 16);
}

// ---- radix pass A: per-tile bucket histogram (+ zero counts/stats) ----
__global__ __launch_bounds__(256) void tile_hist_kernel(const int* __restrict__ dst,
                                                        int* __restrict__ tcnt,
                                                        int* __restrict__ counts,
                                                        float* __restrict__ stats,
                                                        int e, int ntiles, int nbkt, int n) {
  __shared__ int hist[NBKT_MAX];
  int tile = blockIdx.x, tid = threadIdx.x;
  int idx = blockIdx.x * 256 + tid;
  if (idx < n) counts[idx] = 0;          // grid covers N (800*256 >= 100000)
  if (idx < 256) stats[idx] = 0.f;
  for (int b = tid; b < nbkt; b += 256) hist[b] = 0;
  __syncthreads();
  int t0 = tile * TILE_E;
  int tend = t0 + TILE_E; if (tend > e) tend = e;
  for (int i = t0 + tid; i < tend; i += 256)
    atomicAdd(&hist[__builtin_nontemporal_load(&dst[i]) >> BKT_SHIFT], 1);
  __syncthreads();
  for (int b = tid; b < nbkt; b += 256) tcnt[b * ntiles + tile] = hist[b];
}

// ---- radix pass A scatter: reuse tcnt, parallel in-block scan, LDS-staged ----
__global__ __launch_bounds__(256) void tile_scatter_kernel(const int* __restrict__ src,
                                                           const int* __restrict__ dst,
                                                           const int* __restrict__ tcnt,
                                                           const int* __restrict__ toff,
                                                           int2* __restrict__ pedge,
                                                           int e, int ntiles, int nbkt) {
  __shared__ int hb[NBKT_MAX], cnt[NBKT_MAX], gbase[NBKT_MAX];
  __shared__ int2 led[TILE_E];
  int tile = blockIdx.x, tid = threadIdx.x;
  for (int b = tid; b < nbkt; b += 256) {
    hb[b] = tcnt[b * ntiles + tile];
    gbase[b] = toff[b * ntiles + tile];
    cnt[b] = 0;
  }
  __syncthreads();
  if (tid < 64) {  // wave 0: exclusive scan of hb[0..nbkt) (4 buckets/lane)
    int b4 = tid * 4;
    int h0 = (b4 + 0 < nbkt) ? hb[b4 + 0] : 0;
    int h1 = (b4 + 1 < nbkt) ? hb[b4 + 1] : 0;
    int h2 = (b4 + 2 < nbkt) ? hb[b4 + 2] : 0;
    int h3 = (b4 + 3 < nbkt) ? hb[b4 + 3] : 0;
    int local = h0 + h1 + h2 + h3, v = local;
#pragma unroll
    for (int d = 1; d < 64; d <<= 1) {
      int t = __shfl_up(v, d, 64);
      if (tid >= d) v += t;
    }
    int excl = v - local;
    if (b4 + 0 < nbkt) hb[b4 + 0] = excl;
    if (b4 + 1 < nbkt) hb[b4 + 1] = excl + h0;
    if (b4 + 2 < nbkt) hb[b4 + 2] = excl + h0 + h1;
    if (b4 + 3 < nbkt) hb[b4 + 3] = excl + h0 + h1 + h2;
  }
  __syncthreads();
  int t0 = tile * TILE_E;
  int tend = t0 + TILE_E; if (tend > e) tend = e;
  for (int i = t0 + tid; i < tend; i += 256) {
    int s = __builtin_nontemporal_load(&src[i]);
    int d = __builtin_nontemporal_load(&dst[i]);
    int bkt = d >> BKT_SHIFT;
    int slot = hb[bkt] + atomicAdd(&cnt[bkt], 1);
    led[slot] = make_int2(s, d);
  }
  __syncthreads();
  int tc = tend - t0;
  for (int j = tid; j < tc; j += 256) {
    int2 sd = led[j];
    int bkt = sd.y >> BKT_SHIFT;
    pedge[gbase[bkt] + (j - hb[bkt])] = sd;
  }
}

// ---- degree count: 4 blocks/bucket over edge-quarters ----
__global__ __launch_bounds__(256) void deg_count_kernel(const int2* __restrict__ pedge,
                                                        const int* __restrict__ toff,
                                                        int* __restrict__ counts,
                                                        int e, int ntiles, int nbkt, int n) {
  __shared__ int cnt[512];
  int b = blockIdx.x >> 2, qu = blockIdx.x & 3;
  int nb0 = b << BKT_SHIFT;
  int nn = n - nb0; if (nn > 512) nn = 512;
  for (int l = threadIdx.x; l < 512; l += 256) cnt[l] = 0;
  __syncthreads();
  int estart = toff[b * ntiles];
  int eend = (b + 1 < nbkt) ? toff[(b + 1) * ntiles] : e;
  int len = eend - estart;
  int qb = estart + (int)((long long)len * qu / 4);
  int qe = estart + (int)((long long)len * (qu + 1) / 4);
  for (int i = qb + threadIdx.x; i < qe; i += 256)
    atomicAdd(&cnt[pedge[i].y - nb0], 1);
  __syncthreads();
  for (int l = threadIdx.x; l < nn; l += 256) {
    int c = cnt[l];
    if (c) atomicAdd(&counts[nb0 + l], c);
  }
}

// ---- hierarchical exclusive scan (optionally emits dinv = rsqrt(cnt+1)) ----
__global__ __launch_bounds__(1024) void scan1_kernel(const int* __restrict__ counts,
                                                     int* __restrict__ cursor,
                                                     int* __restrict__ bsum,
                                                     float* __restrict__ dinv, int n) {
  __shared__ int wsum[16];
  int tid = threadIdx.x, lane = tid & 63, wid = tid >> 6;
  int idx = blockIdx.x * 1024 + tid;
  int orig = (idx < n) ? counts[idx] : 0;
  if (dinv != nullptr && idx < n) dinv[idx] = rsqrtf((float)(orig + 1));
  int v = orig;
#pragma unroll
  for (int d = 1; d < 64; d <<= 1) {
    int t = __shfl_up(v, d, 64);
    if (lane >= d) v += t;
  }
  if (lane == 63) wsum[wid] = v;
  __syncthreads();
  if (wid == 0 && lane < 16) {
    int s = wsum[lane];
#pragma unroll
    for (int d = 1; d < 16; d <<= 1) {
      int t = __shfl_up(s, d, 64);
      if (lane >= d) s += t;
    }
    wsum[lane] = s;
  }
  __syncthreads();
  int wexcl = (wid == 0) ? 0 : wsum[wid - 1];
  if (idx < n) cursor[idx] = wexcl + (v - orig);
  if (tid == 0) bsum[blockIdx.x] = wsum[15];
}

__global__ __launch_bounds__(256) void scan2_kernel(const int* __restrict__ bsum,
                                                    int* __restrict__ boff, int nb) {
  __shared__ int wsum[4];
  int tid = threadIdx.x, lane = tid & 63, wid = tid >> 6;
  int orig = (tid < nb) ? bsum[tid] : 0;
  int v = orig;
#pragma unroll
  for (int d = 1; d < 64; d <<= 1) {
    int t = __shfl_up(v, d, 64);
    if (lane >= d) v += t;
  }
  if (lane == 63) wsum[wid] = v;
  __syncthreads();
  if (tid == 0) {
    int run = 0;
#pragma unroll
    for (int w = 0; w < 4; ++w) { int t = wsum[w]; wsum[w] = run; run += t; }
  }
  __syncthreads();
  if (tid < nb) boff[tid] = wsum[wid] + (v - orig);
}

__global__ void scan3_kernel(int* __restrict__ cursor, const int* __restrict__ boff, int n) {
  int i = blockIdx.x * blockDim.x + threadIdx.x;
  if (i < n) cursor[i] += boff[i >> 10];
}

// ---- final counting sort: 4 blocks/bucket over node-quarters ----
__global__ __launch_bounds__(256) void bucket_sort_kernel(const int2* __restrict__ pedge,
                                                          const int* __restrict__ toff,
                                                          const int* __restrict__ cursor,
                                                          int* __restrict__ sorted_src,
                                                          int e, int ntiles, int nbkt, int n) {
  __shared__ int lcur[128];
  __shared__ int lsrc[BSORT_CAP];
  int b = blockIdx.x >> 2, qu = blockIdx.x & 3;
  int nb0 = b << BKT_SHIFT;
  int q0 = nb0 + qu * 128;
  if (q0 >= n) return;
  int q1 = q0 + 128; if (q1 > n) q1 = n;
  int qn = q1 - q0;
  int estart = toff[b * ntiles];
  int eend = (b + 1 < nbkt) ? toff[(b + 1) * ntiles] : e;
  int qstart = cursor[q0];
  int qend = (q1 < n) ? cursor[q1] : e;
  for (int l = threadIdx.x; l < qn; l += 256) lcur[l] = cursor[q0 + l] - qstart;
  __syncthreads();
  for (int i = estart + threadIdx.x; i < eend; i += 256) {
    int2 sd = pedge[i];
    unsigned rel = (unsigned)(sd.y - q0);
    if (rel < (unsigned)qn) {
      int pos = atomicAdd(&lcur[rel], 1);
      if (pos < BSORT_CAP) lsrc[pos] = sd.x;
    }
  }
  __syncthreads();
  int qc = qend - qstart; if (qc > BSORT_CAP) qc = BSORT_CAP;
  for (int j = threadIdx.x; j < qc; j += 256) sorted_src[qstart + j] = lsrc[j];
}

// MFMA GEMM + dinv row-scale epilogue, SLICE-MAJOR output:
// Cb[(ct*n + r)*8 + word] since slice == ct for word = ct*8+(m>>1).
// MODE 0: A fp32 row-major (gemm1). MODE 1: A slice-major bf16 + fused BN+ReLU.
template <int MODE>
__global__ __launch_bounds__(256) void gemm_mfma_kernel(const void* __restrict__ Ap,
                                                        const float* __restrict__ W,
                                                        const float* __restrict__ dinv,
                                                        const float* __restrict__ stats,
                                                        const float* __restrict__ gamma,
                                                        const float* __restrict__ beta,
                                                        unsigned* __restrict__ Cb, int n) {
  __shared__ unsigned short WB[16384];  // [kt][ct][nl][q][8 bf16] = 32 KB
  __shared__ float scs[128], shs[128];
  int tid = threadIdx.x;
  if (MODE == 1 && tid < 128) {
    float invN = 1.f / (float)n;
    float mu = stats[tid] * invN;
    float var = stats[128 + tid] * invN - mu * mu;
    float rstd = rsqrtf(var + 1e-5f);
    float s = gamma[tid] * rstd;
    scs[tid] = s;
    shs[tid] = beta[tid] - mu * s;
  }
  for (int idx = tid; idx < 16384; idx += 256) {
    int k = idx >> 7, c = idx & 127;  // W[k][c]
    int kt = k >> 5, q = (k >> 3) & 3, j = k & 7;
    int ct = c >> 4, nl = c & 15;
    WB[(((kt * 8 + ct) * 16 + nl) * 4 + q) * 8 + j] = f32_bf16(W[idx]);
  }
  __syncthreads();
  int lane = tid & 63;
  int m = lane & 15, q = lane >> 4;
  float scr[4][8], shr[4][8];
  if (MODE == 1) {
#pragma unroll
    for (int kt = 0; kt < 4; ++kt)
#pragma unroll
      for (int j = 0; j < 8; ++j) {
        int c = kt * 32 + q * 8 + j;
        scr[kt][j] = scs[c];
        shr[kt][j] = shs[c];
      }
  }
  int wv = (int)((blockIdx.x * 256u + tid) >> 6);
  int nwv = (int)((gridDim.x * 256u) >> 6);
  int ntl = n >> 4;  // n % 16 == 0 here (100000)
  for (int t = wv; t < ntl; t += nwv) {
    int row = t * 16 + m;
    bf16x8 af[4];
    if (MODE == 1) {
      // A word range for kt: W0 = kt*16 + q*4 -> slice = kt*2+(q>>1), pos = (q&1)*4
      const unsigned* Ab = (const unsigned*)Ap;
#pragma unroll
      for (int kt = 0; kt < 4; ++kt) {
        int slice = kt * 2 + (q >> 1);
        const u32x4* Au = (const u32x4*)(Ab + ((size_t)slice * n + row) * 8 + (q & 1) * 4);
        u32x4 w = *Au;
        float y0 = fmaxf(fmaf(scr[kt][0], bf_lo(w.x), shr[kt][0]), 0.f);
        float y1 = fmaxf(fmaf(scr[kt][1], bf_hi(w.x), shr[kt][1]), 0.f);
        float y2 = fmaxf(fmaf(scr[kt][2], bf_lo(w.y), shr[kt][2]), 0.f);
        float y3 = fmaxf(fmaf(scr[kt][3], bf_hi(w.y), shr[kt][3]), 0.f);
        float y4 = fmaxf(fmaf(scr[kt][4], bf_lo(w.z), shr[kt][4]), 0.f);
        float y5 = fmaxf(fmaf(scr[kt][5], bf_hi(w.z), shr[kt][5]), 0.f);
        float y6 = fmaxf(fmaf(scr[kt][6], bf_lo(w.w), shr[kt][6]), 0.f);
        float y7 = fmaxf(fmaf(scr[kt][7], bf_hi(w.w), shr[kt][7]), 0.f);
        union { bf16x8 v; unsigned uu[4]; } uf;
        uf.uu[0] = pack_bf16(y0, y1);
        uf.uu[1] = pack_bf16(y2, y3);
        uf.uu[2] = pack_bf16(y4, y5);
        uf.uu[3] = pack_bf16(y6, y7);
        af[kt] = uf.v;
      }
    } else {
      const float* Arow = (const float*)Ap + (size_t)row * 128 + q * 8;
#pragma unroll
      for (int kt = 0; kt < 4; ++kt) {
        f32x4 a0 = *(const f32x4*)(Arow + kt * 32);
        f32x4 a1 = *(const f32x4*)(Arow + kt * 32 + 4);
        union { bf16x8 v; unsigned short s[8]; } u;
        u.s[0] = f32_bf16(a0.x); u.s[1] = f32_bf16(a0.y);
        u.s[2] = f32_bf16(a0.z); u.s[3] = f32_bf16(a0.w);
        u.s[4] = f32_bf16(a1.x); u.s[5] = f32_bf16(a1.y);
        u.s[6] = f32_bf16(a1.z); u.s[7] = f32_bf16(a1.w);
        af[kt] = u.v;
      }
    }
    f32x4 acc[8];
#pragma unroll
    for (int ct = 0; ct < 8; ++ct) acc[ct] = (f32x4){0.f, 0.f, 0.f, 0.f};
#pragma unroll
    for (int kt = 0; kt < 4; ++kt) {
#pragma unroll
      for (int ct = 0; ct < 8; ++ct) {
        bf16x8 b = *(const bf16x8*)&WB[(((kt * 8 + ct) * 16 + m) * 4 + q) * 8];
        acc[ct] = __builtin_amdgcn_mfma_f32_16x16x32_bf16(af[kt], b, acc[ct], 0, 0, 0);
      }
    }
#pragma unroll
    for (int r4 = 0; r4 < 4; ++r4) {
      int r = t * 16 + q * 4 + r4;
      float dv = dinv[r];
#pragma unroll
      for (int ct = 0; ct < 8; ++ct) {
        float v = acc[ct][r4] * dv;
        float p = __shfl_xor(v, 1, 64);
        if (!(m & 1))
          Cb[((size_t)ct * n + r) * 8 + (m >> 1)] = pack_bf16(v, p);
      }
    }
  }
}

// Slice-partitioned gather: agg[i] = dinv[i]*(g[i] + sum_e g[src_e]).
// Block = (slice = blockIdx&7 ~ XCD, 256-node chunk). Random reads touch only
// this slice's 3.2MB table -> L2-resident. 8 lanes/word x 8 edge-groups:
// one wave-load = 8 edges. Items 0..cnt-1 = edges, item cnt = self.
__global__ __launch_bounds__(256) void gather_kernel(const unsigned* __restrict__ g,
    const int* __restrict__ srcs, const int* __restrict__ cursor,
    const int* __restrict__ counts, const float* __restrict__ dinv,
    unsigned* __restrict__ out, int n) {
  int slice = blockIdx.x & 7;
  int chunk = blockIdx.x >> 3;
  int lane = threadIdx.x & 63;
  int wv = threadIdx.x >> 6;
  int grp = lane >> 3;      // edge group 0..7
  int w = lane & 7;         // word within 32B slice-row
  const unsigned* __restrict__ gs = g + (size_t)slice * n * 8;
  unsigned* __restrict__ os = out + (size_t)slice * n * 8;
  int ibase = chunk * 256;
  int iend = ibase + 256; if (iend > n) iend = n;
  for (int i = ibase + wv; i < iend; i += 4) {
    int beg = cursor[i];
    int cnt = counts[i];
    int cnt2 = cnt + 1;  // + self item
    float di = dinv[i];
    float a0 = 0.f, a1 = 0.f;
    int e = 0;
    for (; e + 16 <= cnt2; e += 16) {  // 2 row-loads in flight
      int kA = e + grp, kB = kA + 8;
      int lA = srcs[beg + kA];  // k==cnt may read 1 past row end (slack)
      int lB = srcs[beg + kB];
      int sA = (kA < cnt) ? lA : i;
      int sB = (kB < cnt) ? lB : i;
      unsigned vA = gs[(size_t)sA * 8 + w];
      unsigned vB = gs[(size_t)sB * 8 + w];
      a0 += bf_lo(vA); a1 += bf_hi(vA);
      a0 += bf_lo(vB); a1 += bf_hi(vB);
    }
    for (; e + 8 <= cnt2; e += 8) {
      int k = e + grp;
      int ls = srcs[beg + k];
      int s = (k < cnt) ? ls : i;
      unsigned v = gs[(size_t)s * 8 + w];
      a0 += bf_lo(v); a1 += bf_hi(v);
    }
    if (e < cnt2) {  // masked partial group
      int k = e + grp;
      int kk = (k < cnt) ? k : 0;
      int ls = srcs[beg + kk];
      int s = (k < cnt) ? ls : i;
      float sel = (k < cnt2) ? 1.f : 0.f;
      unsigned v = gs[(size_t)s * 8 + w];
      a0 = fmaf(sel, bf_lo(v), a0);
      a1 = fmaf(sel, bf_hi(v), a1);
    }
    a0 += __shfl_xor(a0, 8, 64);  a1 += __shfl_xor(a1, 8, 64);
    a0 += __shfl_xor(a0, 16, 64); a1 += __shfl_xor(a1, 16, 64);
    a0 += __shfl_xor(a0, 32, 64); a1 += __shfl_xor(a1, 32, 64);
    if (lane < 8) os[(size_t)i * 8 + lane] = pack_bf16(di * a0, di * a1);
  }
}

// BN stats over slice-major a[8][n][8].
__global__ __launch_bounds__(256) void bn_stats_kernel(const unsigned* __restrict__ a,
                                                       float* __restrict__ stats, int n) {
  int c2 = threadIdx.x & 63;  // word index (channels 2c2, 2c2+1)
  int ph = threadIdx.x >> 6;
  const unsigned* __restrict__ as = a + (size_t)(c2 >> 3) * n * 8 + (c2 & 7);
  float s0 = 0.f, s1 = 0.f, q0 = 0.f, q1 = 0.f;
  for (int r = blockIdx.x * 4 + ph; r < n; r += gridDim.x * 4) {
    unsigned v = as[(size_t)r * 8];
    float x0 = bf_lo(v), x1 = bf_hi(v);
    s0 += x0; s1 += x1; q0 += x0 * x0; q1 += x1 * x1;
  }
  __shared__ float ls[4][64][4];
  ls[ph][c2][0] = s0; ls[ph][c2][1] = s1; ls[ph][c2][2] = q0; ls[ph][c2][3] = q1;
  __syncthreads();
  if (threadIdx.x < 64) {
    int c = threadIdx.x;
    float S0 = 0.f, S1 = 0.f, Q0 = 0.f, Q1 = 0.f;
#pragma unroll
    for (int p = 0; p < 4; ++p) {
      S0 += ls[p][c][0]; S1 += ls[p][c][1]; Q0 += ls[p][c][2]; Q1 += ls[p][c][3];
    }
    atomicAdd(&stats[2 * c], S0);
    atomicAdd(&stats[2 * c + 1], S1);
    atomicAdd(&stats[128 + 2 * c], Q0);
    atomicAdd(&stats[129 + 2 * c], Q1);
  }
}

__global__ void gstart_kernel(const int* __restrict__ batch, int* __restrict__ gstart,
                              int n, int G) {
  int g = blockIdx.x * blockDim.x + threadIdx.x;
  if (g > G) return;
  if (g == G) { gstart[g] = n; return; }
  int lo = 0, hi = n;
  while (lo < hi) {
    int mid = (lo + hi) >> 1;
    if (batch[mid] < g) lo = mid + 1; else hi = mid;
  }
  gstart[g] = lo;
}

// Mean-pool over slice-major a[8][n][8].
__global__ __launch_bounds__(256) void pool_kernel(const unsigned* __restrict__ a,
    const int* __restrict__ gstart, const float* __restrict__ b2,
    float* __restrict__ pooled, int G, int n) {
  int g = blockIdx.x;
  int c2 = threadIdx.x & 63;
  int ph = threadIdx.x >> 6;
  const unsigned* __restrict__ as = a + (size_t)(c2 >> 3) * n * 8 + (c2 & 7);
  int s = gstart[g], e = gstart[g + 1];
  float a0 = 0.f, a1 = 0.f;
  for (int r = s + ph; r < e; r += 4) {
    unsigned v = as[(size_t)r * 8];
    a0 += bf_lo(v); a1 += bf_hi(v);
  }
  __shared__ float ls[4][64][2];
  ls[ph][c2][0] = a0; ls[ph][c2][1] = a1;
  __syncthreads();
  if (threadIdx.x < 64) {
    int c = threadIdx.x;
    float S0 = 0.f, S1 = 0.f;
#pragma unroll
    for (int p = 0; p < 4; ++p) { S0 += ls[p][c][0]; S1 += ls[p][c][1]; }
    int cnt = e - s;
    float inv = (cnt > 0) ? 1.f / (float)cnt : 0.f;
    float2 res;
    res.x = (cnt > 0) ? (S0 * inv + b2[2 * c]) : 0.f;
    res.y = (cnt > 0) ? (S1 * inv + b2[2 * c + 1]) : 0.f;
    ((float2*)(pooled + (size_t)g * 128))[c] = res;
  }
}

__global__ __launch_bounds__(128) void head_kernel(const float* __restrict__ pooled,
    const float* __restrict__ rst, const float* __restrict__ Wg, const float* __restrict__ bg,
    const float* __restrict__ Wr, const float* __restrict__ br, const float* __restrict__ Wc,
    const float* __restrict__ bc, float* __restrict__ out, int G) {
  int g = blockIdx.x;
  int t = threadIdx.x;
  __shared__ float xc[128];
  if (t < 64) {
    float acc = bg[t];
    const float* __restrict__ p = pooled + (size_t)g * 128;
    for (int k = 0; k < 128; ++k) acc = fmaf(p[k], Wg[k * 64 + t], acc);
    xc[t] = fmaxf(acc, 0.f);
  } else {
    int j = t - 64;
    float acc = br[j];
    const float* __restrict__ r = rst + (size_t)g * 64;
    for (int k = 0; k < 64; ++k) acc = fmaf(r[k], Wr[k * 64 + j], acc);
    xc[t] = fmaxf(acc, 0.f);
  }
  __syncthreads();
  if (t < 2) {
    float acc = bc[t];
    for (int j = 0; j < 128; ++j) acc = fmaf(xc[j], Wc[j * 2 + t], acc);
    out[(size_t)g * 2 + t] = acc;
  }
}

extern "C" void kernel_launch(void* const* d_in, const int* in_sizes, int n_in,
                              void* d_out, int out_size, void* d_ws, size_t ws_size,
                              hipStream_t stream) {
  (void)n_in; (void)ws_size;
  const float* x     = (const float*)d_in[0];
  const int*   ei    = (const int*)d_in[1];
  const int*   batch = (const int*)d_in[2];
  const float* rst   = (const float*)d_in[3];
  const float* W1    = (const float*)d_in[5];
  // d_in[6] = b1 — cancels in BatchNorm, skipped
  const float* gamma = (const float*)d_in[7];
  const float* beta  = (const float*)d_in[8];
  const float* W2    = (const float*)d_in[9];
  const float* b2    = (const float*)d_in[10];
  const float* Wg    = (const float*)d_in[11];
  const float* bg    = (const float*)d_in[12];
  const float* Wr    = (const float*)d_in[13];
  const float* br    = (const float*)d_in[14];
  const float* Wc    = (const float*)d_in[15];
  const float* bc    = (const float*)d_in[16];
  float* out = (float*)d_out;

  int N = in_sizes[0] / 128;
  int E = in_sizes[1] / 2;
  int G = out_size / 2;
  const int* esrc = ei;
  const int* edst = ei + E;

  int nbkt = (N + 511) >> BKT_SHIFT;           // 196 for N=100000
  int ntiles = (E + TILE_E - 1) / TILE_E;      // 800 for E=1.6M
  int tlen = nbkt * ntiles;                    // 156800

  char* ws = (char*)d_ws;
  size_t off = 0;
  auto alloc = [&](size_t bytes) -> void* {
    void* p = ws + off;
    off += (bytes + 255) & ~(size_t)255;
    return p;
  };
  unsigned* hb  = (unsigned*)alloc((size_t)N * 64 * 4);  // slice-major bf16 g1/g2
  unsigned* agb = (unsigned*)alloc((size_t)N * 64 * 4);  // slice-major agg1b/agg2b
  int* sorted   = (int*)alloc((size_t)E * 4 + 256);      // +slack: gather reads 1 past
  int2* pedge   = (int2*)alloc((size_t)E * 8);           // bucket-grouped (src,dst)
  int* tcnt     = (int*)alloc((size_t)tlen * 4);
  int* toff     = (int*)alloc((size_t)tlen * 4);
  int* counts   = (int*)alloc((size_t)N * 4);
  int* cursor   = (int*)alloc((size_t)N * 4);             // row STARTS (pristine)
  float* dinv   = (float*)alloc((size_t)N * 4);
  float* stats  = (float*)alloc(256 * 4);
  int* gstart   = (int*)alloc((size_t)(G + 1) * 4);
  float* pooled = (float*)alloc((size_t)G * 128 * 4);
  int* bsum     = (int*)alloc(256 * 4);
  int* boff     = (int*)alloc(256 * 4);
  int* tbsum    = (int*)alloc(256 * 4);
  int* tboff    = (int*)alloc(256 * 4);

  int nscan = (N + 1023) / 1024;
  int ntscan = (tlen + 1023) / 1024;  // 154 <= 256 (scan2 limit)
  int nch = (N + 255) / 256;          // gather node-chunks

  // radix pass: bucket-group edges by dst>>9 (all stores coalesced)
  tile_hist_kernel<<<ntiles, 256, 0, stream>>>(edst, tcnt, counts, stats, E, ntiles, nbkt, N);
  scan1_kernel<<<ntscan, 1024, 0, stream>>>(tcnt, toff, tbsum, nullptr, tlen);
  scan2_kernel<<<1, 256, 0, stream>>>(tbsum, tboff, ntscan);
  scan3_kernel<<<(tlen + 255) / 256, 256, 0, stream>>>(toff, tboff, tlen);
  tile_scatter_kernel<<<ntiles, 256, 0, stream>>>(esrc, edst, tcnt, toff, pedge, E, ntiles, nbkt);
  // degrees + CSR offsets (+dinv fused into scan1)
  deg_count_kernel<<<nbkt * 4, 256, 0, stream>>>(pedge, toff, counts, E, ntiles, nbkt, N);
  scan1_kernel<<<nscan, 1024, 0, stream>>>(counts, cursor, bsum, dinv, N);
  scan2_kernel<<<1, 256, 0, stream>>>(bsum, boff, nscan);
  scan3_kernel<<<(N + 255) / 256, 256, 0, stream>>>(cursor, boff, N);
  // exact counting sort, 4 blocks/bucket (sequential writes)
  bucket_sort_kernel<<<nbkt * 4, 256, 0, stream>>>(pedge, toff, cursor, sorted, E, ntiles, nbkt, N);

  gemm_mfma_kernel<0><<<1024, 256, 0, stream>>>(x, W1, dinv, stats, gamma, beta, hb, N);
  gather_kernel<<<nch * 8, 256, 0, stream>>>(hb, sorted, cursor, counts, dinv, agb, N);

  bn_stats_kernel<<<512, 256, 0, stream>>>(agb, stats, N);

  gemm_mfma_kernel<1><<<1024, 256, 0, stream>>>(agb, W2, dinv, stats, gamma, beta, hb, N);
  gather_kernel<<<nch * 8, 256, 0, stream>>>(hb, sorted, cursor, counts, dinv, agb, N);

  gstart_kernel<<<(G + 1 + 255) / 256, 256, 0, stream>>>(batch, gstart, N, G);
  pool_kernel<<<G, 256, 0, stream>>>(agb, gstart, b2, pooled, G, N);
  head_kernel<<<G, 128, 0, stream>>>(pooled, rst, Wg, bg, Wr, br, Wc, bc, out, G);
}

// Round 11
// 406.521 us; speedup vs baseline: 1.7136x; 1.7136x over previous
//
#include <hip/hip_runtime.h>

// Pipeline (gather tables hb = FP8 e4m3 [n][32 dwords]; aggregates agb = packed
// bf16 pairs [n][64 words], word c = channels 2c,2c+1):
//  tile_hist (+zero counts/stats) -> scan(tcnt) -> tile_scatter (radix: edges
//  bucket-grouped by dst>>9, coalesced writes) -> deg_count -> scan(counts,
//  +dinv) -> bucket_sort (LDS counting sort, sequential writes -> sorted[] CSR)
//  -> gemm<0> (hb = fp8(dinv .* (x@W1)); b1 cancels in BN) -> gather (agg1b bf16)
//  -> bn_stats -> gemm<1> (BN+ReLU fused on A-path; hb = fp8(dinv .* (y1@W2)))
//  -> gather (agg2b) -> gstart -> pool (+b2) -> head
//
// HW laws measured this session:
//  - scattered dword stores: ~40-64B HBM writeback each; L2 never assembles
//    lines -> all sort-pipeline stores are sequential.
//  - gather cost = random-transaction count x service cost (~3.5 TB/s at 256B
//    rows; dword vs dwordx4 identical; 8x32B slicing catastrophic despite
//    L2-resident FETCH). Only bytes/row helps -> fp8 rows (128B).
//  - low-grid kernels (<1 block/CU) are latency-exposed.

typedef __attribute__((ext_vector_type(8))) short bf16x8;
typedef __attribute__((ext_vector_type(4))) float f32x4;
typedef __attribute__((ext_vector_type(2))) float f32x2;
typedef __attribute__((ext_vector_type(2))) unsigned u32x2;
typedef __attribute__((ext_vector_type(4))) unsigned u32x4;

#define NBKT_MAX 256
#define BKT_SHIFT 9            // bucket = dst >> 9 (512 nodes per bucket)
#define TILE_E 2000            // edges per radix tile
#define BSORT_CAP 4096         // LDS staging cap per node-quarter

__device__ __forceinline__ float bf_lo(unsigned u) {
  union { unsigned u; float f; } c; c.u = u << 16; return c.f;
}
__device__ __forceinline__ float bf_hi(unsigned u) {
  union { unsigned u; float f; } c; c.u = u & 0xffff0000u; return c.f;
}
__device__ __forceinline__ unsigned short f32_bf16(float f) {
  union { float f; unsigned u; } c; c.f = f;
  return (unsigned short)((c.u + 0x7fffu + ((c.u >> 16) & 1u)) >> 16);  // RNE
}
__device__ __forceinline__ unsigned pack_bf16(float a, float b) {
  return (unsigned)f32_bf16(a) | ((unsigned)f32_bf16(b) << 16);
}
// 4 fp32 -> 1 dword of fp8 e4m3 (HW convert)
__device__ __forceinline__ unsigned pack_fp8x4(float c0, float c1, float c2, float c3) {
  int w = __builtin_amdgcn_cvt_pk_fp8_f32(c0, c1, 0, false);
  w = __builtin_amdgcn_cvt_pk_fp8_f32(c2, c3, w, true);
  return (unsigned)w;
}

// ---- radix pass A: per-tile bucket histogram (+ zero counts/stats) ----
__global__ __launch_bounds__(256) void tile_hist_kernel(const int* __restrict__ dst,
                                                        int* __restrict__ tcnt,
                                                        int* __restrict__ counts,
                                                        float* __restrict__ stats,
                                                        int e, int ntiles, int nbkt, int n) {
  __shared__ int hist[NBKT_MAX];
  int tile = blockIdx.x, tid = threadIdx.x;
  int idx = blockIdx.x * 256 + tid;
  if (idx < n) counts[idx] = 0;          // grid covers N (800*256 >= 100000)
  if (idx < 256) stats[idx] = 0.f;
  for (int b = tid; b < nbkt; b += 256) hist[b] = 0;
  __syncthreads();
  int t0 = tile * TILE_E;
  int tend = t0 + TILE_E; if (tend > e) tend = e;
  for (int i = t0 + tid; i < tend; i += 256)
    atomicAdd(&hist[__builtin_nontemporal_load(&dst[i]) >> BKT_SHIFT], 1);
  __syncthreads();
  for (int b = tid; b < nbkt; b += 256) tcnt[b * ntiles + tile] = hist[b];
}

// ---- radix pass A scatter: reuse tcnt, parallel in-block scan, LDS-staged ----
__global__ __launch_bounds__(256) void tile_scatter_kernel(const int* __restrict__ src,
                                                           const int* __restrict__ dst,
                                                           const int* __restrict__ tcnt,
                                                           const int* __restrict__ toff,
                                                           int2* __restrict__ pedge,
                                                           int e, int ntiles, int nbkt) {
  __shared__ int hb[NBKT_MAX], cnt[NBKT_MAX], gbase[NBKT_MAX];
  __shared__ int2 led[TILE_E];
  int tile = blockIdx.x, tid = threadIdx.x;
  for (int b = tid; b < nbkt; b += 256) {
    hb[b] = tcnt[b * ntiles + tile];
    gbase[b] = toff[b * ntiles + tile];
    cnt[b] = 0;
  }
  __syncthreads();
  if (tid < 64) {  // wave 0: exclusive scan of hb[0..nbkt) (4 buckets/lane)
    int b4 = tid * 4;
    int h0 = (b4 + 0 < nbkt) ? hb[b4 + 0] : 0;
    int h1 = (b4 + 1 < nbkt) ? hb[b4 + 1] : 0;
    int h2 = (b4 + 2 < nbkt) ? hb[b4 + 2] : 0;
    int h3 = (b4 + 3 < nbkt) ? hb[b4 + 3] : 0;
    int local = h0 + h1 + h2 + h3, v = local;
#pragma unroll
    for (int d = 1; d < 64; d <<= 1) {
      int t = __shfl_up(v, d, 64);
      if (tid >= d) v += t;
    }
    int excl = v - local;
    if (b4 + 0 < nbkt) hb[b4 + 0] = excl;
    if (b4 + 1 < nbkt) hb[b4 + 1] = excl + h0;
    if (b4 + 2 < nbkt) hb[b4 + 2] = excl + h0 + h1;
    if (b4 + 3 < nbkt) hb[b4 + 3] = excl + h0 + h1 + h2;
  }
  __syncthreads();
  int t0 = tile * TILE_E;
  int tend = t0 + TILE_E; if (tend > e) tend = e;
  for (int i = t0 + tid; i < tend; i += 256) {
    int s = __builtin_nontemporal_load(&src[i]);
    int d = __builtin_nontemporal_load(&dst[i]);
    int bkt = d >> BKT_SHIFT;
    int slot = hb[bkt] + atomicAdd(&cnt[bkt], 1);
    led[slot] = make_int2(s, d);
  }
  __syncthreads();
  int tc = tend - t0;
  for (int j = tid; j < tc; j += 256) {
    int2 sd = led[j];
    int bkt = sd.y >> BKT_SHIFT;
    pedge[gbase[bkt] + (j - hb[bkt])] = sd;
  }
}

// ---- degree count: 4 blocks/bucket over edge-quarters ----
__global__ __launch_bounds__(256) void deg_count_kernel(const int2* __restrict__ pedge,
                                                        const int* __restrict__ toff,
                                                        int* __restrict__ counts,
                                                        int e, int ntiles, int nbkt, int n) {
  __shared__ int cnt[512];
  int b = blockIdx.x >> 2, qu = blockIdx.x & 3;
  int nb0 = b << BKT_SHIFT;
  int nn = n - nb0; if (nn > 512) nn = 512;
  for (int l = threadIdx.x; l < 512; l += 256) cnt[l] = 0;
  __syncthreads();
  int estart = toff[b * ntiles];
  int eend = (b + 1 < nbkt) ? toff[(b + 1) * ntiles] : e;
  int len = eend - estart;
  int qb = estart + (int)((long long)len * qu / 4);
  int qe = estart + (int)((long long)len * (qu + 1) / 4);
  for (int i = qb + threadIdx.x; i < qe; i += 256)
    atomicAdd(&cnt[pedge[i].y - nb0], 1);
  __syncthreads();
  for (int l = threadIdx.x; l < nn; l += 256) {
    int c = cnt[l];
    if (c) atomicAdd(&counts[nb0 + l], c);
  }
}

// ---- hierarchical exclusive scan (optionally emits dinv = rsqrt(cnt+1)) ----
__global__ __launch_bounds__(1024) void scan1_kernel(const int* __restrict__ counts,
                                                     int* __restrict__ cursor,
                                                     int* __restrict__ bsum,
                                                     float* __restrict__ dinv, int n) {
  __shared__ int wsum[16];
  int tid = threadIdx.x, lane = tid & 63, wid = tid >> 6;
  int idx = blockIdx.x * 1024 + tid;
  int orig = (idx < n) ? counts[idx] : 0;
  if (dinv != nullptr && idx < n) dinv[idx] = rsqrtf((float)(orig + 1));
  int v = orig;
#pragma unroll
  for (int d = 1; d < 64; d <<= 1) {
    int t = __shfl_up(v, d, 64);
    if (lane >= d) v += t;
  }
  if (lane == 63) wsum[wid] = v;
  __syncthreads();
  if (wid == 0 && lane < 16) {
    int s = wsum[lane];
#pragma unroll
    for (int d = 1; d < 16; d <<= 1) {
      int t = __shfl_up(s, d, 64);
      if (lane >= d) s += t;
    }
    wsum[lane] = s;
  }
  __syncthreads();
  int wexcl = (wid == 0) ? 0 : wsum[wid - 1];
  if (idx < n) cursor[idx] = wexcl + (v - orig);
  if (tid == 0) bsum[blockIdx.x] = wsum[15];
}

__global__ __launch_bounds__(256) void scan2_kernel(const int* __restrict__ bsum,
                                                    int* __restrict__ boff, int nb) {
  __shared__ int wsum[4];
  int tid = threadIdx.x, lane = tid & 63, wid = tid >> 6;
  int orig = (tid < nb) ? bsum[tid] : 0;
  int v = orig;
#pragma unroll
  for (int d = 1; d < 64; d <<= 1) {
    int t = __shfl_up(v, d, 64);
    if (lane >= d) v += t;
  }
  if (lane == 63) wsum[wid] = v;
  __syncthreads();
  if (tid == 0) {
    int run = 0;
#pragma unroll
    for (int w = 0; w < 4; ++w) { int t = wsum[w]; wsum[w] = run; run += t; }
  }
  __syncthreads();
  if (tid < nb) boff[tid] = wsum[wid] + (v - orig);
}

__global__ void scan3_kernel(int* __restrict__ cursor, const int* __restrict__ boff, int n) {
  int i = blockIdx.x * blockDim.x + threadIdx.x;
  if (i < n) cursor[i] += boff[i >> 10];
}

// ---- final counting sort: 4 blocks/bucket over node-quarters ----
__global__ __launch_bounds__(256) void bucket_sort_kernel(const int2* __restrict__ pedge,
                                                          const int* __restrict__ toff,
                                                          const int* __restrict__ cursor,
                                                          int* __restrict__ sorted_src,
                                                          int e, int ntiles, int nbkt, int n) {
  __shared__ int lcur[128];
  __shared__ int lsrc[BSORT_CAP];
  int b = blockIdx.x >> 2, qu = blockIdx.x & 3;
  int nb0 = b << BKT_SHIFT;
  int q0 = nb0 + qu * 128;
  if (q0 >= n) return;
  int q1 = q0 + 128; if (q1 > n) q1 = n;
  int qn = q1 - q0;
  int estart = toff[b * ntiles];
  int eend = (b + 1 < nbkt) ? toff[(b + 1) * ntiles] : e;
  int qstart = cursor[q0];
  int qend = (q1 < n) ? cursor[q1] : e;
  for (int l = threadIdx.x; l < qn; l += 256) lcur[l] = cursor[q0 + l] - qstart;
  __syncthreads();
  for (int i = estart + threadIdx.x; i < eend; i += 256) {
    int2 sd = pedge[i];
    unsigned rel = (unsigned)(sd.y - q0);
    if (rel < (unsigned)qn) {
      int pos = atomicAdd(&lcur[rel], 1);
      if (pos < BSORT_CAP) lsrc[pos] = sd.x;
    }
  }
  __syncthreads();
  int qc = qend - qstart; if (qc > BSORT_CAP) qc = BSORT_CAP;
  for (int j = threadIdx.x; j < qc; j += 256) sorted_src[qstart + j] = lsrc[j];
}

// MFMA GEMM + dinv row-scale epilogue -> FP8 table Cb[n][32 dwords].
// C/D: col=ct*16+m, row=q*4+r4. 3-shfl micro-transpose gives lanes m%4==0 the
// 4 consecutive cols for one fp8 dword.
// MODE 0: A fp32 (gemm1). MODE 1: A packed bf16 agb + fused BN+ReLU on load.
template <int MODE>
__global__ __launch_bounds__(256) void gemm_mfma_kernel(const void* __restrict__ Ap,
                                                        const float* __restrict__ W,
                                                        const float* __restrict__ dinv,
                                                        const float* __restrict__ stats,
                                                        const float* __restrict__ gamma,
                                                        const float* __restrict__ beta,
                                                        unsigned* __restrict__ Cb, int n) {
  __shared__ unsigned short WB[16384];  // [kt][ct][nl][q][8 bf16] = 32 KB
  __shared__ float scs[128], shs[128];
  int tid = threadIdx.x;
  if (MODE == 1 && tid < 128) {
    float invN = 1.f / (float)n;
    float mu = stats[tid] * invN;
    float var = stats[128 + tid] * invN - mu * mu;
    float rstd = rsqrtf(var + 1e-5f);
    float s = gamma[tid] * rstd;
    scs[tid] = s;
    shs[tid] = beta[tid] - mu * s;
  }
  for (int idx = tid; idx < 16384; idx += 256) {
    int k = idx >> 7, c = idx & 127;  // W[k][c]
    int kt = k >> 5, q = (k >> 3) & 3, j = k & 7;
    int ct = c >> 4, nl = c & 15;
    WB[(((kt * 8 + ct) * 16 + nl) * 4 + q) * 8 + j] = f32_bf16(W[idx]);
  }
  __syncthreads();
  int lane = tid & 63;
  int m = lane & 15, q = lane >> 4;
  float scr[4][8], shr[4][8];
  if (MODE == 1) {
#pragma unroll
    for (int kt = 0; kt < 4; ++kt)
#pragma unroll
      for (int j = 0; j < 8; ++j) {
        int c = kt * 32 + q * 8 + j;
        scr[kt][j] = scs[c];
        shr[kt][j] = shs[c];
      }
  }
  int wv = (int)((blockIdx.x * 256u + tid) >> 6);
  int nwv = (int)((gridDim.x * 256u) >> 6);
  int ntl = n >> 4;  // n % 16 == 0 here (100000)
  for (int t = wv; t < ntl; t += nwv) {
    int row = t * 16 + m;
    bf16x8 af[4];
    if (MODE == 1) {
      const u32x4* Au = (const u32x4*)((const unsigned*)Ap + (size_t)row * 64 + q * 4);
#pragma unroll
      for (int kt = 0; kt < 4; ++kt) {
        u32x4 w = Au[kt * 4];
        float y0 = fmaxf(fmaf(scr[kt][0], bf_lo(w.x), shr[kt][0]), 0.f);
        float y1 = fmaxf(fmaf(scr[kt][1], bf_hi(w.x), shr[kt][1]), 0.f);
        float y2 = fmaxf(fmaf(scr[kt][2], bf_lo(w.y), shr[kt][2]), 0.f);
        float y3 = fmaxf(fmaf(scr[kt][3], bf_hi(w.y), shr[kt][3]), 0.f);
        float y4 = fmaxf(fmaf(scr[kt][4], bf_lo(w.z), shr[kt][4]), 0.f);
        float y5 = fmaxf(fmaf(scr[kt][5], bf_hi(w.z), shr[kt][5]), 0.f);
        float y6 = fmaxf(fmaf(scr[kt][6], bf_lo(w.w), shr[kt][6]), 0.f);
        float y7 = fmaxf(fmaf(scr[kt][7], bf_hi(w.w), shr[kt][7]), 0.f);
        union { bf16x8 v; unsigned uu[4]; } uf;
        uf.uu[0] = pack_bf16(y0, y1);
        uf.uu[1] = pack_bf16(y2, y3);
        uf.uu[2] = pack_bf16(y4, y5);
        uf.uu[3] = pack_bf16(y6, y7);
        af[kt] = uf.v;
      }
    } else {
      const float* Arow = (const float*)Ap + (size_t)row * 128 + q * 8;
#pragma unroll
      for (int kt = 0; kt < 4; ++kt) {
        f32x4 a0 = *(const f32x4*)(Arow + kt * 32);
        f32x4 a1 = *(const f32x4*)(Arow + kt * 32 + 4);
        union { bf16x8 v; unsigned short s[8]; } u;
        u.s[0] = f32_bf16(a0.x); u.s[1] = f32_bf16(a0.y);
        u.s[2] = f32_bf16(a0.z); u.s[3] = f32_bf16(a0.w);
        u.s[4] = f32_bf16(a1.x); u.s[5] = f32_bf16(a1.y);
        u.s[6] = f32_bf16(a1.z); u.s[7] = f32_bf16(a1.w);
        af[kt] = u.v;
      }
    }
    f32x4 acc[8];
#pragma unroll
    for (int ct = 0; ct < 8; ++ct) acc[ct] = (f32x4){0.f, 0.f, 0.f, 0.f};
#pragma unroll
    for (int kt = 0; kt < 4; ++kt) {
#pragma unroll
      for (int ct = 0; ct < 8; ++ct) {
        bf16x8 b = *(const bf16x8*)&WB[(((kt * 8 + ct) * 16 + m) * 4 + q) * 8];
        acc[ct] = __builtin_amdgcn_mfma_f32_16x16x32_bf16(af[kt], b, acc[ct], 0, 0, 0);
      }
    }
#pragma unroll
    for (int r4 = 0; r4 < 4; ++r4) {
      int r = t * 16 + q * 4 + r4;
      float dv = dinv[r];
#pragma unroll
      for (int ct = 0; ct < 8; ++ct) {
        float v = acc[ct][r4] * dv;
        float p1 = __shfl_xor(v, 1, 64);   // col m^1
        float p2 = __shfl_xor(v, 2, 64);   // col m^2
        float p3 = __shfl_xor(p1, 2, 64);  // col m^3 (for m%4==0)
        if (!(m & 3))
          Cb[(size_t)r * 32 + ct * 4 + (m >> 2)] = pack_fp8x4(v, p1, p2, p3);
      }
    }
  }
}

// agg[i] = dinv[i] * ( g[i] + sum_e g[src_e] ), g = fp8 rows (128B), pre-scaled
// by dinv in GEMM. 16 lanes x 8B = one row; 4 items/load (grp = lane>>4);
// items 0..cnt-1 = edges, item cnt = self. Output bf16 [n][64 words].
__global__ __launch_bounds__(256) void gather_kernel(const unsigned* __restrict__ g,
    const int* __restrict__ srcs, const int* __restrict__ cursor,
    const int* __restrict__ counts, const float* __restrict__ dinv,
    unsigned* __restrict__ out, int n) {
  int lane = threadIdx.x & 63;
  int grp = lane >> 4;   // item within quad
  int sub = lane & 15;   // 8B sub-block within row (channels 8sub..8sub+7)
  int gw = (int)((blockIdx.x * blockDim.x + threadIdx.x) >> 6);
  int nw = (int)((gridDim.x * blockDim.x) >> 6);
  for (int i0 = gw; i0 < n; i0 += nw) {
    int i = __builtin_amdgcn_readfirstlane(i0);
    int beg = cursor[i];
    int cnt = counts[i];
    int cnt2 = cnt + 1;  // + self item (k == cnt)
    float di = dinv[i];
    float a0 = 0.f, a1 = 0.f, a2 = 0.f, a3 = 0.f;
    float a4 = 0.f, a5 = 0.f, a6 = 0.f, a7 = 0.f;
#define ACC8(W0, W1)                                                       \
    { f32x2 p0 = __builtin_amdgcn_cvt_pk_f32_fp8((int)(W0), false);        \
      f32x2 p1 = __builtin_amdgcn_cvt_pk_f32_fp8((int)(W0), true);         \
      f32x2 p2 = __builtin_amdgcn_cvt_pk_f32_fp8((int)(W1), false);        \
      f32x2 p3 = __builtin_amdgcn_cvt_pk_f32_fp8((int)(W1), true);         \
      a0 += p0.x; a1 += p0.y; a2 += p1.x; a3 += p1.y;                      \
      a4 += p2.x; a5 += p2.y; a6 += p3.x; a7 += p3.y; }
    int e = 0;
    for (; e + 16 <= cnt2; e += 16) {  // 4 row-loads in flight
      int kA = e + grp, kB = kA + 4, kC = kA + 8, kD = kA + 12;
      int lA = srcs[beg + kA];  // k==cnt may read 1 past row end (slack)
      int lB = srcs[beg + kB];
      int lC = srcs[beg + kC];
      int lD = srcs[beg + kD];
      int sA = (kA < cnt) ? lA : i;
      int sB = (kB < cnt) ? lB : i;
      int sC = (kC < cnt) ? lC : i;
      int sD = (kD < cnt) ? lD : i;
      u32x2 vA = *((const u32x2*)(g + ((size_t)sA << 5)) + sub);
      u32x2 vB = *((const u32x2*)(g + ((size_t)sB << 5)) + sub);
      u32x2 vC = *((const u32x2*)(g + ((size_t)sC << 5)) + sub);
      u32x2 vD = *((const u32x2*)(g + ((size_t)sD << 5)) + sub);
      ACC8(vA.x, vA.y) ACC8(vB.x, vB.y) ACC8(vC.x, vC.y) ACC8(vD.x, vD.y)
    }
    for (; e + 4 <= cnt2; e += 4) {
      int k = e + grp;
      int ls = srcs[beg + k];
      int s = (k < cnt) ? ls : i;
      u32x2 v = *((const u32x2*)(g + ((size_t)s << 5)) + sub);
      ACC8(v.x, v.y)
    }
    if (e < cnt2) {  // masked partial quad
      int k = e + grp;
      int kk = (k < cnt) ? k : 0;
      int ls = srcs[beg + kk];
      int s = (k < cnt) ? ls : i;
      float sel = (k < cnt2) ? 1.f : 0.f;
      u32x2 v = *((const u32x2*)(g + ((size_t)s << 5)) + sub);
      f32x2 p0 = __builtin_amdgcn_cvt_pk_f32_fp8((int)v.x, false);
      f32x2 p1 = __builtin_amdgcn_cvt_pk_f32_fp8((int)v.x, true);
      f32x2 p2 = __builtin_amdgcn_cvt_pk_f32_fp8((int)v.y, false);
      f32x2 p3 = __builtin_amdgcn_cvt_pk_f32_fp8((int)v.y, true);
      a0 = fmaf(sel, p0.x, a0); a1 = fmaf(sel, p0.y, a1);
      a2 = fmaf(sel, p1.x, a2); a3 = fmaf(sel, p1.y, a3);
      a4 = fmaf(sel, p2.x, a4); a5 = fmaf(sel, p2.y, a5);
      a6 = fmaf(sel, p3.x, a6); a7 = fmaf(sel, p3.y, a7);
    }
#undef ACC8
    a0 += __shfl_xor(a0, 16, 64); a0 += __shfl_xor(a0, 32, 64);
    a1 += __shfl_xor(a1, 16, 64); a1 += __shfl_xor(a1, 32, 64);
    a2 += __shfl_xor(a2, 16, 64); a2 += __shfl_xor(a2, 32, 64);
    a3 += __shfl_xor(a3, 16, 64); a3 += __shfl_xor(a3, 32, 64);
    a4 += __shfl_xor(a4, 16, 64); a4 += __shfl_xor(a4, 32, 64);
    a5 += __shfl_xor(a5, 16, 64); a5 += __shfl_xor(a5, 32, 64);
    a6 += __shfl_xor(a6, 16, 64); a6 += __shfl_xor(a6, 32, 64);
    a7 += __shfl_xor(a7, 16, 64); a7 += __shfl_xor(a7, 32, 64);
    if (grp == 0) {  // lane sub writes channels 8sub..8sub+7 = words 4sub..4sub+3
      u32x4 o;
      o.x = pack_bf16(di * a0, di * a1);
      o.y = pack_bf16(di * a2, di * a3);
      o.z = pack_bf16(di * a4, di * a5);
      o.w = pack_bf16(di * a6, di * a7);
      *((u32x4*)(out + ((size_t)i << 6)) + sub) = o;
    }
  }
}

__global__ __launch_bounds__(256) void bn_stats_kernel(const unsigned* __restrict__ a,
                                                       float* __restrict__ stats, int n) {
  int c2 = threadIdx.x & 63;
  int ph = threadIdx.x >> 6;
  float s0 = 0.f, s1 = 0.f, q0 = 0.f, q1 = 0.f;
  for (int r = blockIdx.x * 4 + ph; r < n; r += gridDim.x * 4) {
    unsigned v = a[(size_t)r * 64 + c2];
    float x0 = bf_lo(v), x1 = bf_hi(v);
    s0 += x0; s1 += x1; q0 += x0 * x0; q1 += x1 * x1;
  }
  __shared__ float ls[4][64][4];
  ls[ph][c2][0] = s0; ls[ph][c2][1] = s1; ls[ph][c2][2] = q0; ls[ph][c2][3] = q1;
  __syncthreads();
  if (threadIdx.x < 64) {
    int c = threadIdx.x;
    float S0 = 0.f, S1 = 0.f, Q0 = 0.f, Q1 = 0.f;
#pragma unroll
    for (int p = 0; p < 4; ++p) {
      S0 += ls[p][c][0]; S1 += ls[p][c][1]; Q0 += ls[p][c][2]; Q1 += ls[p][c][3];
    }
    atomicAdd(&stats[2 * c], S0);
    atomicAdd(&stats[2 * c + 1], S1);
    atomicAdd(&stats[128 + 2 * c], Q0);
    atomicAdd(&stats[129 + 2 * c], Q1);
  }
}

__global__ void gstart_kernel(const int* __restrict__ batch, int* __restrict__ gstart,
                              int n, int G) {
  int g = blockIdx.x * blockDim.x + threadIdx.x;
  if (g > G) return;
  if (g == G) { gstart[g] = n; return; }
  int lo = 0, hi = n;
  while (lo < hi) {
    int mid = (lo + hi) >> 1;
    if (batch[mid] < g) lo = mid + 1; else hi = mid;
  }
  gstart[g] = lo;
}

__global__ __launch_bounds__(256) void pool_kernel(const unsigned* __restrict__ a,
    const int* __restrict__ gstart, const float* __restrict__ b2,
    float* __restrict__ pooled, int G) {
  int g = blockIdx.x;
  int c2 = threadIdx.x & 63;
  int ph = threadIdx.x >> 6;
  int s = gstart[g], e = gstart[g + 1];
  float a0 = 0.f, a1 = 0.f;
  for (int r = s + ph; r < e; r += 4) {
    unsigned v = a[(size_t)r * 64 + c2];
    a0 += bf_lo(v); a1 += bf_hi(v);
  }
  __shared__ float ls[4][64][2];
  ls[ph][c2][0] = a0; ls[ph][c2][1] = a1;
  __syncthreads();
  if (threadIdx.x < 64) {
    int c = threadIdx.x;
    float S0 = 0.f, S1 = 0.f;
#pragma unroll
    for (int p = 0; p < 4; ++p) { S0 += ls[p][c][0]; S1 += ls[p][c][1]; }
    int cnt = e - s;
    float inv = (cnt > 0) ? 1.f / (float)cnt : 0.f;
    float2 res;
    res.x = (cnt > 0) ? (S0 * inv + b2[2 * c]) : 0.f;
    res.y = (cnt > 0) ? (S1 * inv + b2[2 * c + 1]) : 0.f;
    ((float2*)(pooled + (size_t)g * 128))[c] = res;
  }
}

__global__ __launch_bounds__(128) void head_kernel(const float* __restrict__ pooled,
    const float* __restrict__ rst, const float* __restrict__ Wg, const float* __restrict__ bg,
    const float* __restrict__ Wr, const float* __restrict__ br, const float* __restrict__ Wc,
    const float* __restrict__ bc, float* __restrict__ out, int G) {
  int g = blockIdx.x;
  int t = threadIdx.x;
  __shared__ float xc[128];
  if (t < 64) {
    float acc = bg[t];
    const float* __restrict__ p = pooled + (size_t)g * 128;
    for (int k = 0; k < 128; ++k) acc = fmaf(p[k], Wg[k * 64 + t], acc);
    xc[t] = fmaxf(acc, 0.f);
  } else {
    int j = t - 64;
    float acc = br[j];
    const float* __restrict__ r = rst + (size_t)g * 64;
    for (int k = 0; k < 64; ++k) acc = fmaf(r[k], Wr[k * 64 + j], acc);
    xc[t] = fmaxf(acc, 0.f);
  }
  __syncthreads();
  if (t < 2) {
    float acc = bc[t];
    for (int j = 0; j < 128; ++j) acc = fmaf(xc[j], Wc[j * 2 + t], acc);
    out[(size_t)g * 2 + t] = acc;
  }
}

extern "C" void kernel_launch(void* const* d_in, const int* in_sizes, int n_in,
                              void* d_out, int out_size, void* d_ws, size_t ws_size,
                              hipStream_t stream) {
  (void)n_in; (void)ws_size;
  const float* x     = (const float*)d_in[0];
  const int*   ei    = (const int*)d_in[1];
  const int*   batch = (const int*)d_in[2];
  const float* rst   = (const float*)d_in[3];
  const float* W1    = (const float*)d_in[5];
  // d_in[6] = b1 — cancels in BatchNorm, skipped
  const float* gamma = (const float*)d_in[7];
  const float* beta  = (const float*)d_in[8];
  const float* W2    = (const float*)d_in[9];
  const float* b2    = (const float*)d_in[10];
  const float* Wg    = (const float*)d_in[11];
  const float* bg    = (const float*)d_in[12];
  const float* Wr    = (const float*)d_in[13];
  const float* br    = (const float*)d_in[14];
  const float* Wc    = (const float*)d_in[15];
  const float* bc    = (const float*)d_in[16];
  float* out = (float*)d_out;

  int N = in_sizes[0] / 128;
  int E = in_sizes[1] / 2;
  int G = out_size / 2;
  const int* esrc = ei;
  const int* edst = ei + E;

  int nbkt = (N + 511) >> BKT_SHIFT;           // 196 for N=100000
  int ntiles = (E + TILE_E - 1) / TILE_E;      // 800 for E=1.6M
  int tlen = nbkt * ntiles;                    // 156800

  char* ws = (char*)d_ws;
  size_t off = 0;
  auto alloc = [&](size_t bytes) -> void* {
    void* p = ws + off;
    off += (bytes + 255) & ~(size_t)255;
    return p;
  };
  unsigned* hb  = (unsigned*)alloc((size_t)N * 32 * 4);  // fp8 g1/g2 (128B rows)
  unsigned* agb = (unsigned*)alloc((size_t)N * 64 * 4);  // bf16 agg1b -> agg2b
  int* sorted   = (int*)alloc((size_t)E * 4 + 256);      // +slack: gather reads 1 past
  int2* pedge   = (int2*)alloc((size_t)E * 8);           // bucket-grouped (src,dst)
  int* tcnt     = (int*)alloc((size_t)tlen * 4);
  int* toff     = (int*)alloc((size_t)tlen * 4);
  int* counts   = (int*)alloc((size_t)N * 4);
  int* cursor   = (int*)alloc((size_t)N * 4);             // row STARTS (pristine)
  float* dinv   = (float*)alloc((size_t)N * 4);
  float* stats  = (float*)alloc(256 * 4);
  int* gstart   = (int*)alloc((size_t)(G + 1) * 4);
  float* pooled = (float*)alloc((size_t)G * 128 * 4);
  int* bsum     = (int*)alloc(256 * 4);
  int* boff     = (int*)alloc(256 * 4);
  int* tbsum    = (int*)alloc(256 * 4);
  int* tboff    = (int*)alloc(256 * 4);

  int nscan = (N + 1023) / 1024;
  int ntscan = (tlen + 1023) / 1024;  // 154 <= 256 (scan2 limit)

  // radix pass: bucket-group edges by dst>>9 (all stores coalesced)
  tile_hist_kernel<<<ntiles, 256, 0, stream>>>(edst, tcnt, counts, stats, E, ntiles, nbkt, N);
  scan1_kernel<<<ntscan, 1024, 0, stream>>>(tcnt, toff, tbsum, nullptr, tlen);
  scan2_kernel<<<1, 256, 0, stream>>>(tbsum, tboff, ntscan);
  scan3_kernel<<<(tlen + 255) / 256, 256, 0, stream>>>(toff, tboff, tlen);
  tile_scatter_kernel<<<ntiles, 256, 0, stream>>>(esrc, edst, tcnt, toff, pedge, E, ntiles, nbkt);
  // degrees + CSR offsets (+dinv fused into scan1)
  deg_count_kernel<<<nbkt * 4, 256, 0, stream>>>(pedge, toff, counts, E, ntiles, nbkt, N);
  scan1_kernel<<<nscan, 1024, 0, stream>>>(counts, cursor, bsum, dinv, N);
  scan2_kernel<<<1, 256, 0, stream>>>(bsum, boff, nscan);
  scan3_kernel<<<(N + 255) / 256, 256, 0, stream>>>(cursor, boff, N);
  // exact counting sort, 4 blocks/bucket (sequential writes)
  bucket_sort_kernel<<<nbkt * 4, 256, 0, stream>>>(pedge, toff, cursor, sorted, E, ntiles, nbkt, N);

  gemm_mfma_kernel<0><<<1024, 256, 0, stream>>>(x, W1, dinv, stats, gamma, beta, hb, N);
  gather_kernel<<<4096, 256, 0, stream>>>(hb, sorted, cursor, counts, dinv, agb, N);

  bn_stats_kernel<<<512, 256, 0, stream>>>(agb, stats, N);

  gemm_mfma_kernel<1><<<1024, 256, 0, stream>>>(agb, W2, dinv, stats, gamma, beta, hb, N);
  gather_kernel<<<4096, 256, 0, stream>>>(hb, sorted, cursor, counts, dinv, agb, N);

  gstart_kernel<<<(G + 1 + 255) / 256, 256, 0, stream>>>(batch, gstart, N, G);
  pool_kernel<<<G, 256, 0, stream>>>(agb, gstart, b2, pooled, G);
  head_kernel<<<G, 128, 0, stream>>>(pooled, rst, Wg, bg, Wr, br, Wc, bc, out, G);
}